// Round 1
// 605.627 us; speedup vs baseline: 1.0035x; 1.0035x over previous
//
#include <hip/hip_runtime.h>

// Problem: B=8, C=16, H=32, W=32 -> N=1024, Ho=Wo=16, P=256
// d_out layout: mu_p [128*256 f32] then sigma_p [128*256*256 f32]
//
// V2: coalesced row staging. Previous version did scattered 4B gathers from
// sigma (transaction-bound, ~16B used per 64B line). Since the argmax column
// pattern touches every cache line of each accessed row anyway, we now fetch
// each needed sigma row FULLY COALESCED into LDS (global_load_lds, 16B/lane,
// linear dest) and do the column gather from LDS (ds_read_b32, <=4-way bank
// aliasing on column&31 -> near free). Stores stay coalesced.
//
// Grid: 128 bc * 8 chunks = 1024 blocks x 256 threads = 4 blocks/CU exactly;
// LDS 33KB/block -> 4 blocks/CU resident, inter-block TLP hides barrier drains.

#define BC    128
#define WDIM  32
#define NP    256
#define NN    1024
#define CH    8            // row-chunks per (b,c)
#define RPB   (NP / CH)    // 32 output rows per block
#define RST   8            // rows staged in LDS per barrier pair

typedef __attribute__((address_space(3))) void lds_void;
typedef const __attribute__((address_space(1))) void g_void;

__global__ __launch_bounds__(256) void fused_kernel(
    const float* __restrict__ mu,
    const float* __restrict__ sigma,
    float* __restrict__ out_mu,     // [BC*NP]
    float* __restrict__ out_sigma)  // [BC*NP*NP]
{
    int bc    = blockIdx.x >> 3;
    int chunk = blockIdx.x & 7;
    int i0    = chunk * RPB;
    int t     = threadIdx.x;        // pooled position / output column

    __shared__ int   s_idx[NP];
    __shared__ float s_rows[RST][NN];   // 8 rows x 4KB = 32KB

    // --- pooled max + first-occurrence argmax for position t ---
    int ho = t >> 4, wo = t & 15;
    const float* m = mu + (size_t)bc * NN;
    int r0 = 2 * ho, c0 = 2 * wo;
    float v00 = m[r0 * WDIM + c0];
    float v01 = m[r0 * WDIM + c0 + 1];
    float v10 = m[(r0 + 1) * WDIM + c0];
    float v11 = m[(r0 + 1) * WDIM + c0 + 1];
    float best = v00; int k = 0;
    if (v01 > best) { best = v01; k = 1; }
    if (v10 > best) { best = v10; k = 2; }
    if (v11 > best) { best = v11; k = 3; }
    int fidx = (r0 + (k >> 1)) * WDIM + (c0 + (k & 1));
    s_idx[t] = fidx;
    if (chunk == 0) out_mu[bc * NP + t] = best;
    __syncthreads();

    int cj = s_idx[t];                       // my output column's sigma column
    const float* sg = sigma + (size_t)bc * NN * NN;
    float* ob = out_sigma + ((size_t)bc * NP + i0) * NP;

    // --- staged row gather: RPB rows in RPB/RST barrier pairs ---
    for (int s = 0; s < RPB / RST; ++s) {
        // stage RST full rows, fully coalesced, async global->LDS (16B/lane).
        // LDS dest is linear in t: wave-uniform base + lane*16 — the HW pattern.
#pragma unroll
        for (int l = 0; l < RST; ++l) {
            int ri = s_idx[i0 + s * RST + l];           // LDS broadcast, uniform per l
            __builtin_amdgcn_global_load_lds(
                (g_void*)(sg + (size_t)ri * NN + 4 * t),
                (lds_void*)(&s_rows[l][4 * t]),
                16, 0, 0);
        }
        __syncthreads();   // drains vmcnt -> rows visible in LDS

        // gather: out[row, t] = row[cj]; LDS read b32 + coalesced 4B store
#pragma unroll
        for (int l = 0; l < RST; ++l) {
            ob[(size_t)(s * RST + l) * NP + t] = s_rows[l][cj];
        }
        __syncthreads();   // protect s_rows before next stage overwrites
    }
}

extern "C" void kernel_launch(void* const* d_in, const int* in_sizes, int n_in,
                              void* d_out, int out_size, void* d_ws, size_t ws_size,
                              hipStream_t stream) {
    const float* mu    = (const float*)d_in[0];
    const float* sigma = (const float*)d_in[1];
    float* out = (float*)d_out;
    fused_kernel<<<BC * CH, 256, 0, stream>>>(mu, sigma, out, out + BC * NP);
}